// Round 9
// baseline (362.641 us; speedup 1.0000x reference)
//
#include <hip/hip_runtime.h>

// BERT self-attention fused forward, MI355X (gfx950)
// B=4, S=2048, E=768, H=12, D=64
// Round 9 = resubmit (infra timeouts in rounds 5/7/8; kernel unchanged since r5+fix):
//  - attn: 8 waves x 16 q (qblock 128), grid 768 = 3 blocks/CU, 24 waves/CU.
//    exp2-domain softmax (Q pre-scaled by 0.125*log2e, masks folded via fma),
//    native bf16 casts for P-pack, s_setprio around MFMA clusters.
//  - gemm: BK=64 (half the barriers, 32 MFMA per stage phase).

typedef __bf16 bf16x8 __attribute__((ext_vector_type(8)));
typedef __bf16 bf16x4 __attribute__((ext_vector_type(4)));
typedef float f32x4 __attribute__((ext_vector_type(4)));
typedef unsigned short u16x8 __attribute__((ext_vector_type(8)));

#define MFMA16(a, b, c) __builtin_amdgcn_mfma_f32_16x16x32_bf16((a), (b), (c), 0, 0, 0)

__device__ __forceinline__ float exp2_fast(float x) {
    float r;
    asm("v_exp_f32 %0, %1" : "=v"(r) : "v"(x));   // r = 2^x (handles -1e30 -> 0)
    return r;
}

__device__ __forceinline__ unsigned short f32_to_bf16(float f) {
    unsigned int u = __builtin_bit_cast(unsigned int, f);
    u += 0x7FFFu + ((u >> 16) & 1u);   // round-to-nearest-even
    return (unsigned short)(u >> 16);
}

__device__ __forceinline__ void gload_lds16(const void* g, void* l) {
    __builtin_amdgcn_global_load_lds(
        (const __attribute__((address_space(1))) void*)g,
        (__attribute__((address_space(3))) void*)l, 16, 0, 0);
}

__global__ __launch_bounds__(256) void cvt_f32_bf16(const float* __restrict__ src,
                                                    unsigned short* __restrict__ dst, int n4) {
    int i = blockIdx.x * 256 + threadIdx.x;
    if (i < n4) {
        const float4 v = reinterpret_cast<const float4*>(src)[i];
        ushort4 o;
        o.x = f32_to_bf16(v.x);
        o.y = f32_to_bf16(v.y);
        o.z = f32_to_bf16(v.z);
        o.w = f32_to_bf16(v.w);
        reinterpret_cast<ushort4*>(dst)[i] = o;
    }
}

__global__ __launch_bounds__(256) void cvt_weights(const float* __restrict__ Wq,
                                                   const float* __restrict__ Wk,
                                                   const float* __restrict__ Wv,
                                                   unsigned short* __restrict__ Wb) {
    int i = blockIdx.x * 256 + threadIdx.x;   // 0 .. 3*147456-1
    const float* src;
    int local = i;
    if (i < 147456) {
        src = Wq;
    } else if (i < 294912) {
        src = Wk; local = i - 147456;
    } else {
        src = Wv; local = i - 294912;
    }
    const float4 v = reinterpret_cast<const float4*>(src)[local];
    ushort4 o;
    o.x = f32_to_bf16(v.x);
    o.y = f32_to_bf16(v.y);
    o.z = f32_to_bf16(v.z);
    o.w = f32_to_bf16(v.w);
    reinterpret_cast<ushort4*>(Wb)[i] = o;
}

// QKV GEMM: out[m][n] = sum_k X[m][k]*W[n][k] + bias[n]
// M=8192, N=2304, K=768. Block 256 (4 waves 2x2), tile 128x128, BK=64.
// LDS rows 128B with XOR-swizzled 16B chunks (chunk = slot ^ (row&7)).
__global__ __launch_bounds__(256) void qkv_gemm(const unsigned short* __restrict__ Xb,
                                                const unsigned short* __restrict__ Wb,
                                                const float* __restrict__ bq,
                                                const float* __restrict__ bk,
                                                const float* __restrict__ bv,
                                                unsigned short* __restrict__ Qb,
                                                unsigned short* __restrict__ Kb,
                                                unsigned short* __restrict__ Vb) {
    const int K = 768;
    __shared__ __align__(16) unsigned short Abuf[128 * 64];   // 16 KB
    __shared__ __align__(16) unsigned short Bbuf[128 * 64];   // 16 KB

    const int lane = threadIdx.x & 63;
    const int w    = threadIdx.x >> 6;
    const int col  = lane & 15;
    const int g    = lane >> 4;
    const int m0 = blockIdx.y * 128;
    const int n0 = blockIdx.x * 128;
    const int wm = w >> 1, wn = w & 1;

    const int lrow   = lane >> 3;                    // 0..7
    const int lchunk = (lane & 7) ^ (lrow & 7);      // swizzled 16B chunk
    const unsigned short* gA = Xb + (size_t)(m0 + w * 32 + lrow) * K + lchunk * 8;
    const unsigned short* gB = Wb + (size_t)(n0 + w * 32 + lrow) * K + lchunk * 8;

    f32x4 acc[4][4] = {};
    for (int k0 = 0; k0 < K; k0 += 64) {
        __syncthreads();
#pragma unroll
        for (int c = 0; c < 4; ++c) {
            gload_lds16(gA + (size_t)(c * 8) * K + k0, (char*)Abuf + w * 4096 + c * 1024);
            gload_lds16(gB + (size_t)(c * 8) * K + k0, (char*)Bbuf + w * 4096 + c * 1024);
        }
        __syncthreads();
#pragma unroll
        for (int kst = 0; kst < 2; ++kst) {
            bf16x8 a[4], bfr[4];
#pragma unroll
            for (int t = 0; t < 4; ++t) {
                const int ra = wm * 64 + t * 16 + col;
                const int rb = wn * 64 + t * 16 + col;
                a[t]   = *reinterpret_cast<const bf16x8*>(
                    (const char*)Abuf + ra * 128 + (((g + 4 * kst) ^ (ra & 7)) << 4));
                bfr[t] = *reinterpret_cast<const bf16x8*>(
                    (const char*)Bbuf + rb * 128 + (((g + 4 * kst) ^ (rb & 7)) << 4));
            }
#pragma unroll
            for (int mi = 0; mi < 4; ++mi)
#pragma unroll
                for (int ni = 0; ni < 4; ++ni)
                    acc[mi][ni] = MFMA16(a[mi], bfr[ni], acc[mi][ni]);
        }
    }

    const int which = n0 / 768;  // 0=Q,1=K,2=V (uniform: 768 % 128 == 0)
    const float* bias = (which == 0) ? bq : (which == 1) ? bk : bv;
    // Q pre-scaled by 1/sqrt(64) * log2(e) -> softmax runs in exp2 domain
    const float scale = (which == 0) ? 0.18033688011112042f : 1.0f;
    unsigned short* dst = (which == 0) ? Qb : (which == 1) ? Kb : Vb;

#pragma unroll
    for (int ni = 0; ni < 4; ++ni) {
        const int n = n0 + wn * 64 + ni * 16 + col;
        const int e = n - which * 768;
        const int h = e >> 6;
        const int d = e & 63;
        const float bb = bias[e];
#pragma unroll
        for (int mi = 0; mi < 4; ++mi)
#pragma unroll
            for (int i = 0; i < 4; ++i) {
                const int m   = m0 + wm * 64 + mi * 16 + 4 * g + i;
                const int bh  = (m >> 11) * 12 + h;
                const int srw = m & 2047;
                const float v = (acc[mi][ni][i] + bb) * scale;
                dst[((size_t)bh * 2048 + srw) * 64 + d] = f32_to_bf16(v);
            }
    }
}

// V row-major [bh][s][64] -> Vt [bh][64][2048], 64x64 LDS tiles
__global__ __launch_bounds__(256) void transpose_v(const unsigned short* __restrict__ Vb,
                                                   unsigned short* __restrict__ Vt) {
    __shared__ unsigned short T[64][72];
    const int bh = blockIdx.y;
    const int s0 = blockIdx.x * 64;
    const int t  = threadIdx.x;
    const int r  = t >> 2;          // 0..63
    const int c0 = (t & 3) * 16;    // 0,16,32,48

    const unsigned short* src = Vb + ((size_t)bh * 2048 + s0 + r) * 64 + c0;
    u16x8 a = *reinterpret_cast<const u16x8*>(src);
    u16x8 b = *reinterpret_cast<const u16x8*>(src + 8);
#pragma unroll
    for (int j = 0; j < 8; ++j) {
        T[c0 + j][r]     = a[j];
        T[c0 + 8 + j][r] = b[j];
    }
    __syncthreads();
    unsigned short* dstp = Vt + ((size_t)bh * 64 + r) * 2048 + s0 + c0;
    *reinterpret_cast<u16x8*>(dstp)     = *reinterpret_cast<const u16x8*>(&T[r][c0]);
    *reinterpret_cast<u16x8*>(dstp + 8) = *reinterpret_cast<const u16x8*>(&T[r][c0 + 8]);
}

// Flash attention. Grid 768 (48 bh x 16 qtiles), block 512 = 8 waves,
// wave owns 16 q rows. K/V LDS-staged double-buffered; exp2-domain softmax.
__global__ __launch_bounds__(512, 6) void attn_kernel(const unsigned short* __restrict__ Qb,
                                                      const unsigned short* __restrict__ Kb,
                                                      const unsigned short* __restrict__ Vt,
                                                      const float* __restrict__ amask,
                                                      const float* __restrict__ dmask,
                                                      float* __restrict__ out) {
    const int S = 2048, H = 12;
    const float L2E = 1.4426950408889634f;
    const int lane = threadIdx.x & 63;
    const int w    = threadIdx.x >> 6;   // 0..7
    const int col  = lane & 15;
    const int g    = lane >> 4;

    // bijective XCD swizzle: 768 = 8 XCD x 96; consecutive logicals share bh
    const int phys    = blockIdx.x;
    const int logical = (phys & 7) * 96 + (phys >> 3);
    const int bh = logical >> 4;       // 0..47
    const int qt = logical & 15;
    const int b  = bh / H;
    const int h  = bh % H;
    const int q0 = qt * 128 + w * 16;  // wave's first q row
    const int q  = q0 + col;           // this lane's q row

    // K/V tiles: 128B rows, 16B chunks XOR-swizzled (chunk = slot ^ (row&7))
    __shared__ __align__(16) unsigned short Kl[2][4096];   // [64 kv][64 d]
    __shared__ __align__(16) unsigned short Vl[2][4096];   // [64 d][64 kv]
    __shared__ __align__(16) unsigned short Pl[8][16][72]; // per-wave P

    // Q B-fragments (pre-scaled by 0.125*log2e)
    bf16x8 qf[2];
#pragma unroll
    for (int kst = 0; kst < 2; ++kst)
        qf[kst] = *reinterpret_cast<const bf16x8*>(
            Qb + ((size_t)bh * S + q) * 64 + kst * 32 + 8 * g);

    f32x4 octx[4] = {};
    float m_run = -1e30f, l_run = 0.0f;

    const float* dmr = dmask + (size_t)b * S * S + (size_t)q * S;
    const float* amr = amask + (size_t)b * S;

    // staging: wave w covers rows 8w..8w+7 of each tile (1KB per gload pair)
    const int lrow   = lane >> 3;                 // 0..7
    const int lchunk = (lane & 7) ^ (lrow & 7);
#define STAGE(buf, KV)                                                              \
    {                                                                               \
        const int base = w * 1024;                                                  \
        gload_lds16((const char*)(Kb + ((size_t)bh * S + (KV) + w * 8 + lrow) * 64) \
                        + lchunk * 16,                                              \
                    (char*)&Kl[buf][0] + base);                                     \
        gload_lds16((const char*)(Vt + ((size_t)bh * 64 + w * 8 + lrow) * S + (KV)) \
                        + lchunk * 16,                                              \
                    (char*)&Vl[buf][0] + base);                                     \
    }

    STAGE(0, 0)
    __syncthreads();

    int cur = 0;
    for (int t = 0; t < 32; ++t) {
        const int kv = t * 64;
        if (t + 1 < 32) STAGE(cur ^ 1, kv + 64)

        // dmask prefetch (HBM/L2 latency hides under QK^T)
        f32x4 dm[4];
#pragma unroll
        for (int s = 0; s < 4; ++s)
            dm[s] = *reinterpret_cast<const f32x4*>(dmr + kv + s * 16 + 4 * g);

        // ---- QK^T (swapped): A=K frag (m=kv), B=Q (n=q) -> sc col=q, row=kv ----
        f32x4 sc[4] = {};
        __builtin_amdgcn_s_setprio(1);
#pragma unroll
        for (int s = 0; s < 4; ++s) {
            const int row = s * 16 + col;
#pragma unroll
            for (int kst = 0; kst < 2; ++kst) {
                bf16x8 kf = *reinterpret_cast<const bf16x8*>(
                    (const char*)&Kl[cur][0] + row * 128 + (((g + 4 * kst) ^ (col & 7)) << 4));
                sc[s] = MFMA16(kf, qf[kst], sc[s]);
            }
        }
        __builtin_amdgcn_s_setprio(0);

        // masks folded into exp2 domain: sc_log2 += (dm + am) * log2e
#pragma unroll
        for (int s = 0; s < 4; ++s) {
            f32x4 a4 = *reinterpret_cast<const f32x4*>(amr + kv + s * 16 + 4 * g);
            sc[s] += (dm[s] + a4) * L2E;
        }
        // softmax over kv (16 in-lane + cross-g reduce), exp2 domain
        float tm = sc[0][0];
#pragma unroll
        for (int s = 0; s < 4; ++s)
#pragma unroll
            for (int i = 0; i < 4; ++i) tm = fmaxf(tm, sc[s][i]);
        tm = fmaxf(tm, __shfl_xor(tm, 16));
        tm = fmaxf(tm, __shfl_xor(tm, 32));
        const bool grow = tm > m_run;
        const float mn = fmaxf(m_run, tm);
        float rs = 0.0f;
#pragma unroll
        for (int s = 0; s < 4; ++s)
#pragma unroll
            for (int i = 0; i < 4; ++i) {
                const float p = exp2_fast(sc[s][i] - mn);
                sc[s][i] = p;
                rs += p;
            }
        rs += __shfl_xor(rs, 16);
        rs += __shfl_xor(rs, 32);
        if (__any(grow)) {
            const float sf = exp2_fast(m_run - mn);
            l_run = l_run * sf + rs;
            m_run = mn;
#pragma unroll
            for (int ds_ = 0; ds_ < 4; ++ds_) octx[ds_] *= sf;
        } else {
            l_run += rs;
        }
        // pack P^T -> per-wave LDS (native RTNE casts)
#pragma unroll
        for (int s = 0; s < 4; ++s) {
            bf16x4 p;
            p[0] = (__bf16)sc[s][0];
            p[1] = (__bf16)sc[s][1];
            p[2] = (__bf16)sc[s][2];
            p[3] = (__bf16)sc[s][3];
            *reinterpret_cast<bf16x4*>(&Pl[w][col][s * 16 + 4 * g]) = p;
        }

        // ---- PV (swapped): A=V^T frag (m=d), B=P (n=q) ----
        bf16x8 pb[2];
#pragma unroll
        for (int kst = 0; kst < 2; ++kst)
            pb[kst] = *reinterpret_cast<const bf16x8*>(&Pl[w][col][kst * 32 + 8 * g]);
        __builtin_amdgcn_s_setprio(1);
#pragma unroll
        for (int ds_ = 0; ds_ < 4; ++ds_) {
            const int row = ds_ * 16 + col;
#pragma unroll
            for (int kst = 0; kst < 2; ++kst) {
                bf16x8 vf = *reinterpret_cast<const bf16x8*>(
                    (const char*)&Vl[cur][0] + row * 128 + (((g + 4 * kst) ^ (col & 7)) << 4));
                octx[ds_] = MFMA16(vf, pb[kst], octx[ds_]);
            }
        }
        __builtin_amdgcn_s_setprio(0);

        __syncthreads();
        cur ^= 1;
    }

    // epilogue: out[b][q][h*64 + d]
    const float inv = 1.0f / l_run;
    const size_t ob = ((size_t)b * S + q) * 768 + h * 64;
#pragma unroll
    for (int ds_ = 0; ds_ < 4; ++ds_) {
        f32x4 o = octx[ds_] * inv;
        *reinterpret_cast<f32x4*>(out + ob + ds_ * 16 + 4 * g) = o;
    }
#undef STAGE
}

extern "C" void kernel_launch(void* const* d_in, const int* in_sizes, int n_in,
                              void* d_out, int out_size, void* d_ws, size_t ws_size,
                              hipStream_t stream) {
    const float* hidden = (const float*)d_in[0];
    const float* amask  = (const float*)d_in[1];
    const float* dmask  = (const float*)d_in[2];
    const float* Wq     = (const float*)d_in[3];
    const float* bq     = (const float*)d_in[4];
    const float* Wk     = (const float*)d_in[5];
    const float* bk     = (const float*)d_in[6];
    const float* Wv     = (const float*)d_in[7];
    const float* bv     = (const float*)d_in[8];
    float* out = (float*)d_out;

    // workspace layout (bf16 elements); Vt reuses Xb region (dead after gemm)
    unsigned short* Xb = (unsigned short*)d_ws;      // 8192*768
    unsigned short* Wb = Xb + 6291456;               // 2304*768
    unsigned short* Qb = Wb + 1769472;               // 48*2048*64
    unsigned short* Kb = Qb + 6291456;
    unsigned short* Vb = Kb + 6291456;               // row-major V
    unsigned short* Vt = Xb;                         // transposed [bh][d][s]

    cvt_f32_bf16<<<6144, 256, 0, stream>>>(hidden, Xb, 1572864);
    cvt_weights<<<1728, 256, 0, stream>>>(Wq, Wk, Wv, Wb);
    qkv_gemm<<<dim3(18, 64), 256, 0, stream>>>(Xb, Wb, bq, bk, bv, Qb, Kb, Vb);
    transpose_v<<<dim3(32, 48), 256, 0, stream>>>(Vb, Vt);
    attn_kernel<<<768, 512, 0, stream>>>(Qb, Kb, Vt, amask, dmask, out);
}